// Round 14
// baseline (592.294 us; speedup 1.0000x reference)
//
#include <hip/hip_runtime.h>
#include <hip/hip_bf16.h>

#define B_DIM 8192
#define IN_DIM 2048
#define H_DIM 2048
#define K_DIM 4096   // IN + H
#define N4H   8192   // 4*H
#define NT    64     // K tiles of BK=64

using short8 = __attribute__((ext_vector_type(8))) short;
using f32x4  = __attribute__((ext_vector_type(4))) float;
using u16x4  = __attribute__((ext_vector_type(4))) unsigned short;

__device__ __forceinline__ unsigned short f2bf(float f) {
  union { float f; unsigned int u; } v; v.f = f;
  unsigned int u = v.u;
  return (unsigned short)((u + 0x7FFFu + ((u >> 16) & 1u)) >> 16);
}

// ---------------------------------------------------------------------------
// pack_a: A_bf16[b][k] = bf16( k<2048 ? inp[b][k] : h0[b][k-2048] ), [8192][4096]
// ---------------------------------------------------------------------------
__global__ __launch_bounds__(256) void pack_a(const float* __restrict__ inp,
                                              const float* __restrict__ h0,
                                              unsigned short* __restrict__ Ap) {
  size_t idx = ((size_t)blockIdx.x * 256 + threadIdx.x) * 4;
  int b = (int)(idx >> 12);
  int k = (int)(idx & 4095);
  const float* src = (k < IN_DIM) ? (inp + (size_t)b * IN_DIM + k)
                                  : (h0  + (size_t)b * H_DIM + (k - IN_DIM));
  float4 v = *(const float4*)src;
  u16x4 o = { f2bf(v.x), f2bf(v.y), f2bf(v.z), f2bf(v.w) };
  *(u16x4*)&Ap[idx] = o;
}

// ---------------------------------------------------------------------------
// pack_b: B^T bf16 [8192 packed cols][4096 K], gate-interleaved columns.
// packed col c -> orig col = gate*2048 + j, gate=(c>>4)&3, j=(c>>6)*16+(c&15)
// ---------------------------------------------------------------------------
__global__ __launch_bounds__(256) void pack_b(const float* __restrict__ W,
                                              const float* __restrict__ U,
                                              unsigned short* __restrict__ Bp) {
  __shared__ float tile[64][17];
  const int c0 = blockIdx.x * 16;
  const int k0 = blockIdx.y * 64;
  const int gate  = (c0 >> 4) & 3;
  const int jbase = (c0 >> 6) * 16;
  const int colbase = gate * 2048 + jbase;
  const int t  = threadIdx.x;
  const int cc = t & 15;
  const int r0 = t >> 4;
#pragma unroll
  for (int rr = 0; rr < 4; ++rr) {
    int k = k0 + r0 + rr * 16;
    const float* src = (k < IN_DIM) ? (W + (size_t)k * N4H)
                                    : (U + (size_t)(k - IN_DIM) * N4H);
    tile[r0 + rr * 16][cc] = src[colbase + cc];
  }
  __syncthreads();
  const int c   = t >> 4;
  const int kk0 = (t & 15) * 4;
  u16x4 o = { f2bf(tile[kk0 + 0][c]), f2bf(tile[kk0 + 1][c]),
              f2bf(tile[kk0 + 2][c]), f2bf(tile[kk0 + 3][c]) };
  *(u16x4*)&Bp[(size_t)(c0 + c) * K_DIM + k0 + kk0] = o;
}

// ---------------------------------------------------------------------------
// Fused GEMM + LSTM epilogue, 256x256 tile, BK=64, 8 waves, MFMA 16x16x32.
// R13 = R12 staging/vmcnt ledger + m201 PHASE DISCIPLINE (read-current,
// dual-barrier-isolated MFMA clusters, 8 barriers/tile):
//   q0: RD bf(kt)+af0(kt); STAGE A0,A2(+1);          bar; MFMA(0); bar
//   q1: RD af1(kt);        STAGE B0..B3(+1); vmcnt(6);bar; MFMA(1); bar
//   q2: RD af2(kt);        STAGE A1,A3(+1);           bar; MFMA(2); bar
//   q3: RD af3(kt);        vmcnt(2);                  bar; MFMA(3); bar
// Mechanism (m201/m196): reads issued pre-barrier for the CURRENT phase;
// each wave's lgkm-completion staggers (LDS pipe serves the burst serially)
// so MFMA clusters skew per-wave and overlap other waves' LDS traffic,
// bounded by the trailing barrier.
// Drain ledger (= R12): q1's vmcnt(6) drains A1A3(kt) [3-ph lead, 2 barriers
// before their first read at q2(kt)]; q3's vmcnt(2) drains A0A2(kt+1) [3-ph]
// + B0..B3(kt+1) [2-ph], leaving A1A3(kt+1)=2 in flight. Tile kt+1 is
// published by q3(kt)'s vmcnt(2)+barriers before q0(kt+1) reads it.
// WAR: every STAGE into db is >=1 barrier after the last read of that
// region (tile kt-1's reads are lgkm-consumed by their MFMA pre-bar2).
// Tail keeps vmcnt(0)+barrier before reading A1/A3(63)  [R5 race fix].
// LDS: buf*32768 + {A:0, B:16384}; 64-row units of [r][64], 3-bit XOR swizzle
// (kgroup ^= row&7), staged via pre-swizzled global source (linear LDS dest).
// ---------------------------------------------------------------------------
__global__ __launch_bounds__(512, 2) void lstm_gemm(
    const unsigned short* __restrict__ Ap,
    const unsigned short* __restrict__ Bp,
    const float* __restrict__ c0,
    const float* __restrict__ b_w,
    const float* __restrict__ b_u,
    float* __restrict__ out) {
  __shared__ unsigned short lds[65536];   // 128 KiB

  const int t     = threadIdx.x;
  const int lane  = t & 63;
  const int wid   = t >> 6;     // 0..7
  const int wr    = wid >> 2;   // 0..1  (M half)
  const int wc    = wid & 3;    // 0..3  (N quarter)
  const int laneM = lane & 15;
  const int laneG = lane >> 4;  // 0..3

  // XCD-bijective swizzle (nwg = 1024, divisible by 8)
  const int wg  = blockIdx.x;
  const int swz = (wg & 7) * 128 + (wg >> 3);
  const int bm  = swz >> 5;
  const int bn  = swz & 31;

  // ---- staging source (pre-swizzled global address, linear LDS dest) ----
  const int rt   = t >> 3;                 // 0..63 (row within 64-row unit)
  const int gt   = t & 7;                  // kgroup
  const int gsw  = gt ^ (rt & 7);          // 3-bit pre-swizzle
  const unsigned short* gA = Ap + (size_t)(bm * 256 + rt) * K_DIM + gsw * 8;
  const unsigned short* gB = Bp + (size_t)(bn * 256 + rt) * K_DIM + gsw * 8;

#define STAGE(gptr, ldsoff)                                                   \
  __builtin_amdgcn_global_load_lds(                                           \
      (const __attribute__((address_space(1))) void*)(gptr),                  \
      (__attribute__((address_space(3))) void*)&lds[(ldsoff) + t * 8], 16, 0, 0)

#define VMCNT(n) asm volatile("s_waitcnt vmcnt(" #n ")" ::: "memory")
#define BARF()                                                                \
  do {                                                                        \
    asm volatile("" ::: "memory");                                            \
    __builtin_amdgcn_s_barrier();                                             \
    asm volatile("" ::: "memory");                                            \
  } while (0)

  // ---- fragment read offsets (swizzled ds_read) ----
  const int sbit = laneM & 7;              // row&7
  int aoff[2], boff[2];
#pragma unroll
  for (int kk = 0; kk < 2; ++kk) {
    aoff[kk] = wr * 8192 + laneM * 64 + ((kk * 4 + laneG) ^ sbit) * 8;
    boff[kk] = 16384 + (wc >> 1) * 8192 + ((wc & 1) * 64 + laneM) * 64
               + ((kk * 4 + laneG) ^ sbit) * 8;
  }

#define RD_AF(BASE, PH)                                                       \
  _Pragma("unroll")                                                           \
  for (int i = 0; i < 2; ++i)                                                 \
    _Pragma("unroll")                                                         \
    for (int kk = 0; kk < 2; ++kk)                                            \
      af[i][kk] = *(const short8*)&lds[(BASE) + aoff[kk] + (2 * (PH) + i) * 1024];

#define RD_BF(BASE)                                                           \
  _Pragma("unroll")                                                           \
  for (int n = 0; n < 4; ++n)                                                 \
    _Pragma("unroll")                                                         \
    for (int kk = 0; kk < 2; ++kk)                                            \
      bfr[n][kk] = *(const short8*)&lds[(BASE) + boff[kk] + n * 1024];

#define MFMA16(Q)                                                             \
  __builtin_amdgcn_s_setprio(1);                                              \
  _Pragma("unroll")                                                           \
  for (int i = 0; i < 2; ++i)                                                 \
    _Pragma("unroll")                                                         \
    for (int n = 0; n < 4; ++n)                                               \
      _Pragma("unroll")                                                       \
      for (int kk = 0; kk < 2; ++kk)                                          \
        acc[2 * (Q) + i][n] = __builtin_amdgcn_mfma_f32_16x16x32_bf16(        \
            af[i][kk], bfr[n][kk], acc[2 * (Q) + i][n], 0, 0, 0);             \
  __builtin_amdgcn_s_setprio(0)

  f32x4 acc[8][4];
#pragma unroll
  for (int m = 0; m < 8; ++m)
#pragma unroll
    for (int n = 0; n < 4; ++n)
      acc[m][n] = (f32x4){0.f, 0.f, 0.f, 0.f};

  short8 af[2][2], bfr[4][2];

  // ---- bias preload, force-drained so the K-loop vmcnt ledger stays exact --
  const int j = (bn * 4 + wc) * 16 + laneM;
  float bias[4];
#pragma unroll
  for (int g = 0; g < 4; ++g)
    bias[g] = b_w[g * 2048 + j] + b_u[g * 2048 + j];
  asm volatile("s_waitcnt vmcnt(0)" ::: "memory");

  // ---- prologue: stage tile 0 in ledger order A0,A2,B0..B3,A1,A3 ----
  STAGE(gA,               0);
  STAGE(gA + 128 * K_DIM, 8192);
  STAGE(gB,               16384);
  STAGE(gB +  64 * K_DIM, 16384 + 4096);
  STAGE(gB + 128 * K_DIM, 16384 + 8192);
  STAGE(gB + 192 * K_DIM, 16384 + 12288);
  STAGE(gA +  64 * K_DIM, 4096);
  STAGE(gA + 192 * K_DIM, 12288);
  VMCNT(2);               // drain A0,A2,B0..B3 ; leave {A1,A3}(0)
  BARF();

  // ---- main loop: compute tile kt, stage tile kt+1 ----
#pragma unroll 1
  for (int kt = 0; kt < NT - 1; ++kt) {
    const int cb = (kt & 1) << 15;
    const int db = cb ^ 32768;
    const unsigned short* gA1 = gA + (kt + 1) * 64;
    const unsigned short* gB1 = gB + (kt + 1) * 64;
    // q0
    RD_BF(cb);
    RD_AF(cb, 0);
    STAGE(gA1,               db + 0);
    STAGE(gA1 + 128 * K_DIM, db + 8192);
    BARF();
    MFMA16(0);
    BARF();
    // q1
    RD_AF(cb, 1);
    STAGE(gB1,               db + 16384);
    STAGE(gB1 +  64 * K_DIM, db + 16384 + 4096);
    STAGE(gB1 + 128 * K_DIM, db + 16384 + 8192);
    STAGE(gB1 + 192 * K_DIM, db + 16384 + 12288);
    VMCNT(6);               // drain A1,A3(kt)  [3-phase lead]
    BARF();
    MFMA16(1);
    BARF();
    // q2
    RD_AF(cb, 2);
    STAGE(gA1 +  64 * K_DIM, db + 4096);
    STAGE(gA1 + 192 * K_DIM, db + 12288);
    BARF();
    MFMA16(2);
    BARF();
    // q3
    RD_AF(cb, 3);
    VMCNT(2);               // drain A0,A2(+1) [3-ph], B0..B3(+1) [2-ph]
    BARF();
    MFMA16(3);
    BARF();
  }

  // ---- tail tile (NT-1), cb = 32768, no staging ----
  {
    RD_BF(32768);
    RD_AF(32768, 0);
    MFMA16(0);
    RD_AF(32768, 1);
    MFMA16(1);
    VMCNT(0);               // drain own A1,A3(63) slices...
    BARF();                 // ...and make OTHER waves' drained slices visible
    RD_AF(32768, 2);
    MFMA16(2);
    RD_AF(32768, 3);
    MFMA16(3);
  }

  // ---- fused LSTM epilogue ----
  // packed col = bn*256 + wc*64 + nn*16 + laneM -> gate = nn, j = (bn*4+wc)*16+laneM
  const int rbase = bm * 256 + wr * 128 + laneG * 4;
  float* outH = out;
  float* outC = out + (size_t)B_DIM * H_DIM;
#pragma unroll
  for (int m = 0; m < 8; ++m) {
#pragma unroll
    for (int r = 0; r < 4; ++r) {
      const int bi = rbase + m * 16 + r;
      const size_t off = (size_t)bi * H_DIM + j;
      float ig = acc[m][0][r] + bias[0];
      float fg = acc[m][1][r] + bias[1];
      float og = acc[m][2][r] + bias[2];
      float gg = acc[m][3][r] + bias[3];
      float iv = 1.f / (1.f + __expf(-ig));
      float fv = 1.f / (1.f + __expf(-fg));
      float ov = 1.f / (1.f + __expf(-og));
      float gv = 2.f / (1.f + __expf(-2.f * gg)) - 1.f;
      float cv = fv * c0[off] + iv * gv;
      float tc = 2.f / (1.f + __expf(-2.f * cv)) - 1.f;
      outH[off] = ov * tc;
      outC[off] = cv;
    }
  }
}

// ---------------------------------------------------------------------------
extern "C" void kernel_launch(void* const* d_in, const int* in_sizes, int n_in,
                              void* d_out, int out_size, void* d_ws, size_t ws_size,
                              hipStream_t stream) {
  const float* inp = (const float*)d_in[0];
  const float* h0  = (const float*)d_in[1];
  const float* c0  = (const float*)d_in[2];
  const float* W   = (const float*)d_in[3];
  const float* b_w = (const float*)d_in[4];
  const float* U   = (const float*)d_in[5];
  const float* b_u = (const float*)d_in[6];
  float* out = (float*)d_out;

  unsigned short* Ap = (unsigned short*)d_ws;          // 64 MiB
  unsigned short* Bp = Ap + (size_t)B_DIM * K_DIM;     // +64 MiB

  pack_a<<<(B_DIM * K_DIM / 4) / 256, 256, 0, stream>>>(inp, h0, Ap);
  dim3 gb(N4H / 16, K_DIM / 64);
  pack_b<<<gb, 256, 0, stream>>>(W, U, Bp);
  lstm_gemm<<<1024, 512, 0, stream>>>(Ap, Bp, c0, b_w, b_u, out);
}

// Round 15
// 562.526 us; speedup vs baseline: 1.0529x; 1.0529x over previous
//
#include <hip/hip_runtime.h>
#include <hip/hip_bf16.h>

#define B_DIM 8192
#define IN_DIM 2048
#define H_DIM 2048
#define K_DIM 4096   // IN + H
#define N4H   8192   // 4*H
#define NT    64     // K tiles of BK=64

using short8 = __attribute__((ext_vector_type(8))) short;
using f32x4  = __attribute__((ext_vector_type(4))) float;
using u16x4  = __attribute__((ext_vector_type(4))) unsigned short;

__device__ __forceinline__ unsigned short f2bf(float f) {
  union { float f; unsigned int u; } v; v.f = f;
  unsigned int u = v.u;
  return (unsigned short)((u + 0x7FFFu + ((u >> 16) & 1u)) >> 16);
}

// ---------------------------------------------------------------------------
// pack_a: A_bf16[b][k] = bf16( k<2048 ? inp[b][k] : h0[b][k-2048] ), [8192][4096]
// ---------------------------------------------------------------------------
__global__ __launch_bounds__(256) void pack_a(const float* __restrict__ inp,
                                              const float* __restrict__ h0,
                                              unsigned short* __restrict__ Ap) {
  size_t idx = ((size_t)blockIdx.x * 256 + threadIdx.x) * 4;
  int b = (int)(idx >> 12);
  int k = (int)(idx & 4095);
  const float* src = (k < IN_DIM) ? (inp + (size_t)b * IN_DIM + k)
                                  : (h0  + (size_t)b * H_DIM + (k - IN_DIM));
  float4 v = *(const float4*)src;
  u16x4 o = { f2bf(v.x), f2bf(v.y), f2bf(v.z), f2bf(v.w) };
  *(u16x4*)&Ap[idx] = o;
}

// ---------------------------------------------------------------------------
// pack_b: B^T bf16 [8192 packed cols][4096 K], gate-interleaved columns.
// packed col c -> orig col = gate*2048 + j, gate=(c>>4)&3, j=(c>>6)*16+(c&15)
// ---------------------------------------------------------------------------
__global__ __launch_bounds__(256) void pack_b(const float* __restrict__ W,
                                              const float* __restrict__ U,
                                              unsigned short* __restrict__ Bp) {
  __shared__ float tile[64][17];
  const int c0 = blockIdx.x * 16;
  const int k0 = blockIdx.y * 64;
  const int gate  = (c0 >> 4) & 3;
  const int jbase = (c0 >> 6) * 16;
  const int colbase = gate * 2048 + jbase;
  const int t  = threadIdx.x;
  const int cc = t & 15;
  const int r0 = t >> 4;
#pragma unroll
  for (int rr = 0; rr < 4; ++rr) {
    int k = k0 + r0 + rr * 16;
    const float* src = (k < IN_DIM) ? (W + (size_t)k * N4H)
                                    : (U + (size_t)(k - IN_DIM) * N4H);
    tile[r0 + rr * 16][cc] = src[colbase + cc];
  }
  __syncthreads();
  const int c   = t >> 4;
  const int kk0 = (t & 15) * 4;
  u16x4 o = { f2bf(tile[kk0 + 0][c]), f2bf(tile[kk0 + 1][c]),
              f2bf(tile[kk0 + 2][c]), f2bf(tile[kk0 + 3][c]) };
  *(u16x4*)&Bp[(size_t)(c0 + c) * K_DIM + k0 + kk0] = o;
}

// ---------------------------------------------------------------------------
// Fused GEMM + LSTM epilogue, 256x256 tile, BK=64, 8 waves, MFMA 16x16x32.
// R14 = R12 ledger with the two NON-ESSENTIAL barriers removed
// (2 barriers + 2 counted vmcnts per tile, read-ahead preserved):
//   q0: STAGE A0,A2(+1); RD af1(kt,1);              MFMA(0,af0)
//   q1: STAGE B0..B3(+1); VMCNT(6); bar; RD af0(kt,2); MFMA(1,af1)
//   q2: STAGE A1,A3(+1); RD af1(kt,3);              MFMA(2,af0)
//   q3: VMCNT(2); bar; RD af0(kt+1,0)[db]; MFMA(3,af1); RD bf(kt+1)[db]
// Why q0/q2 barriers were removable (R12 ledger audit):
//  - visibility: af1(kt,1) reads unit A0/A2(kt), published at q3(kt-1)'s
//    vmcnt(2)+bar; af1(kt,3) reads unit A1/A3(kt), published at q1(kt)'s
//    vmcnt(6)+bar. No read depends on the removed barriers.
//  - WAR: A0A2 re-stage q0(kt) vs last reads q0/q3(kt-1): bars q1,q3(kt-1)
//    between; A1A3 re-stage q2(kt) vs reads q1/q2(kt-1): bars q3(kt-1),
//    q1(kt); B re-stage q1(kt) vs read q3(kt-2): >=2 bars. All >=2.
// Two long free-run spans per tile (2x16-MFMA clusters + reads + stages
// each) let waves skew so LDS and MFMA pipes overlap instead of
// alternating (R9-vs-R8 evidence; R13 falsified tight-barrier lockstep).
// In-flight ledger (issue order A0A2 | B0..B3 | A1A3): enter q0 with
// {A1A3(kt)}=2; q0:+2; q1:+4=8, vmcnt(6) drains A1A3(kt) [3-ph lead];
// q2:+2=8; q3: vmcnt(2) drains A0A2(kt+1) [3-ph] + B0..B3(kt+1) [2-ph].
// Tail keeps vmcnt(0)+barrier before reading A1/A3(63)  [R5 race fix].
// LDS: buf*32768 + {A:0, B:16384}; 64-row units of [r][64], 3-bit XOR swizzle
// (kgroup ^= row&7), staged via pre-swizzled global source (linear LDS dest).
// ---------------------------------------------------------------------------
__global__ __launch_bounds__(512, 2) void lstm_gemm(
    const unsigned short* __restrict__ Ap,
    const unsigned short* __restrict__ Bp,
    const float* __restrict__ c0,
    const float* __restrict__ b_w,
    const float* __restrict__ b_u,
    float* __restrict__ out) {
  __shared__ unsigned short lds[65536];   // 128 KiB

  const int t     = threadIdx.x;
  const int lane  = t & 63;
  const int wid   = t >> 6;     // 0..7
  const int wr    = wid >> 2;   // 0..1  (M half)
  const int wc    = wid & 3;    // 0..3  (N quarter)
  const int laneM = lane & 15;
  const int laneG = lane >> 4;  // 0..3

  // XCD-bijective swizzle (nwg = 1024, divisible by 8)
  const int wg  = blockIdx.x;
  const int swz = (wg & 7) * 128 + (wg >> 3);
  const int bm  = swz >> 5;
  const int bn  = swz & 31;

  // ---- staging source (pre-swizzled global address, linear LDS dest) ----
  const int rt   = t >> 3;                 // 0..63 (row within 64-row unit)
  const int gt   = t & 7;                  // kgroup
  const int gsw  = gt ^ (rt & 7);          // 3-bit pre-swizzle
  const unsigned short* gA = Ap + (size_t)(bm * 256 + rt) * K_DIM + gsw * 8;
  const unsigned short* gB = Bp + (size_t)(bn * 256 + rt) * K_DIM + gsw * 8;

#define STAGE(gptr, ldsoff)                                                   \
  __builtin_amdgcn_global_load_lds(                                           \
      (const __attribute__((address_space(1))) void*)(gptr),                  \
      (__attribute__((address_space(3))) void*)&lds[(ldsoff) + t * 8], 16, 0, 0)

#define VMCNT(n) asm volatile("s_waitcnt vmcnt(" #n ")" ::: "memory")
#define BARF()                                                                \
  do {                                                                        \
    asm volatile("" ::: "memory");                                            \
    __builtin_amdgcn_s_barrier();                                             \
    asm volatile("" ::: "memory");                                            \
  } while (0)

  // ---- fragment read offsets (swizzled ds_read) ----
  const int sbit = laneM & 7;              // row&7
  int aoff[2], boff[2];
#pragma unroll
  for (int kk = 0; kk < 2; ++kk) {
    aoff[kk] = wr * 8192 + laneM * 64 + ((kk * 4 + laneG) ^ sbit) * 8;
    boff[kk] = 16384 + (wc >> 1) * 8192 + ((wc & 1) * 64 + laneM) * 64
               + ((kk * 4 + laneG) ^ sbit) * 8;
  }

#define RD_AF(AF, BASE, PH)                                                   \
  _Pragma("unroll")                                                           \
  for (int i = 0; i < 2; ++i)                                                 \
    _Pragma("unroll")                                                         \
    for (int kk = 0; kk < 2; ++kk)                                            \
      AF[i][kk] = *(const short8*)&lds[(BASE) + aoff[kk] + (2 * (PH) + i) * 1024];

#define RD_BF(BASE)                                                           \
  _Pragma("unroll")                                                           \
  for (int n = 0; n < 4; ++n)                                                 \
    _Pragma("unroll")                                                         \
    for (int kk = 0; kk < 2; ++kk)                                            \
      bfr[n][kk] = *(const short8*)&lds[(BASE) + boff[kk] + n * 1024];

#define MFMA16(Q, AF)                                                         \
  __builtin_amdgcn_s_setprio(1);                                              \
  _Pragma("unroll")                                                           \
  for (int i = 0; i < 2; ++i)                                                 \
    _Pragma("unroll")                                                         \
    for (int n = 0; n < 4; ++n)                                               \
      _Pragma("unroll")                                                       \
      for (int kk = 0; kk < 2; ++kk)                                          \
        acc[2 * (Q) + i][n] = __builtin_amdgcn_mfma_f32_16x16x32_bf16(        \
            AF[i][kk], bfr[n][kk], acc[2 * (Q) + i][n], 0, 0, 0);             \
  __builtin_amdgcn_s_setprio(0)

  f32x4 acc[8][4];
#pragma unroll
  for (int m = 0; m < 8; ++m)
#pragma unroll
    for (int n = 0; n < 4; ++n)
      acc[m][n] = (f32x4){0.f, 0.f, 0.f, 0.f};

  short8 af0[2][2], af1[2][2], bfr[4][2];

  // ---- bias preload, force-drained so the K-loop vmcnt ledger stays exact --
  const int j = (bn * 4 + wc) * 16 + laneM;
  float bias[4];
#pragma unroll
  for (int g = 0; g < 4; ++g)
    bias[g] = b_w[g * 2048 + j] + b_u[g * 2048 + j];
  asm volatile("s_waitcnt vmcnt(0)" ::: "memory");

  // ---- prologue: stage tile 0 in ledger order A0,A2,B0..B3,A1,A3 ----
  STAGE(gA,               0);
  STAGE(gA + 128 * K_DIM, 8192);
  STAGE(gB,               16384);
  STAGE(gB +  64 * K_DIM, 16384 + 4096);
  STAGE(gB + 128 * K_DIM, 16384 + 8192);
  STAGE(gB + 192 * K_DIM, 16384 + 12288);
  STAGE(gA +  64 * K_DIM, 4096);
  STAGE(gA + 192 * K_DIM, 12288);
  VMCNT(2);               // drain A0,A2,B0..B3 ; leave {A1,A3}(0)
  BARF();
  RD_AF(af0, 0, 0);       // phase-0 A frags of tile 0
  RD_BF(0);               // all B frags of tile 0

  // ---- main loop: compute tile kt, stage tile kt+1 ----
#pragma unroll 1
  for (int kt = 0; kt < NT - 1; ++kt) {
    const int cb = (kt & 1) << 15;
    const int db = cb ^ 32768;
    const unsigned short* gA1 = gA + (kt + 1) * 64;
    const unsigned short* gB1 = gB + (kt + 1) * 64;
    // q0  (no barrier: A0A2(kt) published at q3(kt-1); WAR gap >=2 bars)
    STAGE(gA1,               db + 0);
    STAGE(gA1 + 128 * K_DIM, db + 8192);
    RD_AF(af1, cb, 1);
    MFMA16(0, af0);
    // q1
    STAGE(gB1,               db + 16384);
    STAGE(gB1 +  64 * K_DIM, db + 16384 + 4096);
    STAGE(gB1 + 128 * K_DIM, db + 16384 + 8192);
    STAGE(gB1 + 192 * K_DIM, db + 16384 + 12288);
    VMCNT(6);               // drain A1,A3(kt)  [3-phase lead]
    BARF();
    RD_AF(af0, cb, 2);
    MFMA16(1, af1);
    // q2  (no barrier: A1A3(kt) published at q1(kt); WAR gap >=2 bars)
    STAGE(gA1 +  64 * K_DIM, db + 4096);
    STAGE(gA1 + 192 * K_DIM, db + 12288);
    RD_AF(af1, cb, 3);
    MFMA16(2, af0);
    // q3
    VMCNT(2);               // drain A0,A2(+1) [3-ph], B0..B3(+1) [2-ph]
    BARF();
    RD_AF(af0, db, 0);      // phase-0 A frags of tile kt+1
    MFMA16(3, af1);
    RD_BF(db);              // B frags of tile kt+1 (after MFMA16(3): bfr anti-dep)
  }

  // ---- tail tile (NT-1), cb = 32768, no staging ----
  {
    RD_AF(af1, 32768, 1);
    MFMA16(0, af0);
    VMCNT(0);               // drain own A1,A3(63) slices...
    BARF();                 // ...and make OTHER waves' drained slices visible
    RD_AF(af0, 32768, 2);
    MFMA16(1, af1);
    RD_AF(af1, 32768, 3);
    MFMA16(2, af0);
    MFMA16(3, af1);
  }

  // ---- fused LSTM epilogue ----
  // packed col = bn*256 + wc*64 + nn*16 + laneM -> gate = nn, j = (bn*4+wc)*16+laneM
  const int rbase = bm * 256 + wr * 128 + laneG * 4;
  float* outH = out;
  float* outC = out + (size_t)B_DIM * H_DIM;
#pragma unroll
  for (int m = 0; m < 8; ++m) {
#pragma unroll
    for (int r = 0; r < 4; ++r) {
      const int bi = rbase + m * 16 + r;
      const size_t off = (size_t)bi * H_DIM + j;
      float ig = acc[m][0][r] + bias[0];
      float fg = acc[m][1][r] + bias[1];
      float og = acc[m][2][r] + bias[2];
      float gg = acc[m][3][r] + bias[3];
      float iv = 1.f / (1.f + __expf(-ig));
      float fv = 1.f / (1.f + __expf(-fg));
      float ov = 1.f / (1.f + __expf(-og));
      float gv = 2.f / (1.f + __expf(-2.f * gg)) - 1.f;
      float cv = fv * c0[off] + iv * gv;
      float tc = 2.f / (1.f + __expf(-2.f * cv)) - 1.f;
      outH[off] = ov * tc;
      outC[off] = cv;
    }
  }
}

// ---------------------------------------------------------------------------
extern "C" void kernel_launch(void* const* d_in, const int* in_sizes, int n_in,
                              void* d_out, int out_size, void* d_ws, size_t ws_size,
                              hipStream_t stream) {
  const float* inp = (const float*)d_in[0];
  const float* h0  = (const float*)d_in[1];
  const float* c0  = (const float*)d_in[2];
  const float* W   = (const float*)d_in[3];
  const float* b_w = (const float*)d_in[4];
  const float* U   = (const float*)d_in[5];
  const float* b_u = (const float*)d_in[6];
  float* out = (float*)d_out;

  unsigned short* Ap = (unsigned short*)d_ws;          // 64 MiB
  unsigned short* Bp = Ap + (size_t)B_DIM * K_DIM;     // +64 MiB

  pack_a<<<(B_DIM * K_DIM / 4) / 256, 256, 0, stream>>>(inp, h0, Ap);
  dim3 gb(N4H / 16, K_DIM / 64);
  pack_b<<<gb, 256, 0, stream>>>(W, U, Bp);
  lstm_gemm<<<1024, 512, 0, stream>>>(Ap, Bp, c0, b_w, b_u, out);
}